// Round 24
// baseline (174.736 us; speedup 1.0000x reference)
//
#include <hip/hip_runtime.h>
#include <hip/hip_fp16.h>
#include <math.h>

#define NEG_SLOPE 0.2f
#define LCAP 8192   // LDS csr capacity per bucket (avg 4096)

__device__ __forceinline__ float lrelu(float x) { return x > 0.f ? x : NEG_SLOPE * x; }

// Order-preserving float<->uint encoding so unsigned atomicMax == float max.
__device__ __forceinline__ unsigned encf(float f) {
    unsigned u = __float_as_uint(f);
    return (u & 0x80000000u) ? ~u : (u | 0x80000000u);
}
__device__ __forceinline__ float decf(unsigned u) {
    return __uint_as_float((u & 0x80000000u) ? (u ^ 0x80000000u) : ~u);
}

// Phase A + dst-histogram + gmax1 block-reduction (merged).
// Grid MUST be G=256 blocks x 512 threads: counts[j*G + blockIdx] layout is
// shared with scatterS. gmax1 must be zeroed (memset) before this kernel.
// Packs the per-node 32B gather row: xa32[8 words] =
//   {x[0..6] fp16 + pad (4 words), asrc1[0..3] f32 (4 words)}.
__global__ void __launch_bounds__(512)
phaseAH(const float* __restrict__ x, const float* __restrict__ W1,
        const float* __restrict__ a_src, const float* __restrict__ a_dst,
        const int* __restrict__ dst,
        unsigned* __restrict__ xa32, float* __restrict__ adst1,
        float* __restrict__ eloop1,
        int* __restrict__ counts, unsigned* __restrict__ gmax1,
        int N, int E, int nbuck) {
    __shared__ int hist[1024];
    __shared__ unsigned bmax1[4];
    int tid = threadIdx.x;
    for (int j = tid; j < nbuck; j += 512) hist[j] = 0;
    if (tid < 4) bmax1[tid] = 0u;
    __syncthreads();

    // histogram over this block's edge slice (bucket = dst >> 7)
    int per = (E + gridDim.x - 1) / gridDim.x;
    int i0 = blockIdx.x * per, i1 = min(E, i0 + per);
    for (int i = i0 + tid; i < i1; i += 512)
        atomicAdd(&hist[dst[i] >> 7], 1);

    // phaseA over this block's node slice (wave per node)
    int npb = (N + gridDim.x - 1) / gridDim.x;
    int n0 = blockIdx.x * npb, n1 = min(N, n0 + npb);
    int lane = tid & 63;
    int head = lane >> 4, c = lane & 15;
    for (int node = n0 + (tid >> 6); node < n1; node += 8) {
        float h = 0.f;
        #pragma unroll
        for (int k = 0; k < 7; k++) h += x[node * 7 + k] * W1[k * 64 + lane];

        float s = h * a_src[lane];
        float d = h * a_dst[lane];
        #pragma unroll
        for (int m = 8; m >= 1; m >>= 1) {
            s += __shfl_xor(s, m);
            d += __shfl_xor(d, m);
        }
        // pack x as fp16 pairs into words 0..3 of the row
        float xl = (lane < 7) ? x[node * 7 + lane] : 0.f;
        float xn = __shfl(xl, lane + 1);
        if (lane < 8 && !(lane & 1)) {
            __half2 hp = __floats2half2_rn(xl, xn);
            xa32[(size_t)node * 8 + (lane >> 1)] = *(unsigned*)&hp;
        }
        if (c == 0) {
            xa32[(size_t)node * 8 + 4 + head] = __float_as_uint(s);
            adst1[node * 4 + head] = d;
            eloop1[node * 4 + head] = lrelu(s + d);
            atomicMax(&bmax1[head], encf(s));   // LDS block-level max
        }
    }
    __syncthreads();
    for (int j = tid; j < nbuck; j += 512)
        counts[j * gridDim.x + blockIdx.x] = hist[j];
    if (tid < 4) atomicMax(&gmax1[tid], bmax1[tid]);
}

// Exclusive scan over counts (2 kernels; final add folded into consumers).
__global__ void scan1(const int* __restrict__ in, int* __restrict__ outv,
                      int* __restrict__ blockSum, int n) {
    __shared__ int sm[256];
    int tid = threadIdx.x;
    int i = blockIdx.x * 256 + tid;
    int v = (i < n) ? in[i] : 0;
    sm[tid] = v;
    __syncthreads();
    for (int off = 1; off < 256; off <<= 1) {
        int t = sm[tid];
        int add = (tid >= off) ? sm[tid - off] : 0;
        __syncthreads();
        sm[tid] = t + add;
        __syncthreads();
    }
    if (i < n) outv[i] = sm[tid] - v;     // block-local exclusive
    if (tid == 255) blockSum[blockIdx.x] = sm[255];
}

__global__ void scan2(int* __restrict__ blockSum, int nb) {
    __shared__ int sm[1024];
    int tid = threadIdx.x;
    int v = (tid < nb) ? blockSum[tid] : 0;
    sm[tid] = v;
    __syncthreads();
    for (int off = 1; off < 1024; off <<= 1) {
        int t = sm[tid];
        int add = (tid >= off) ? sm[tid - off] : 0;
        __syncthreads();
        sm[tid] = t + add;
        __syncthreads();
    }
    if (tid < nb) blockSum[tid] = sm[tid] - v;  // exclusive
}

// scatterS: LDS cursors seeded from (ocounts + blockSum); LDS atomics only.
// ebuf entry packed: src (17b) | local-node-id (7b) << 17.
__global__ void scatterS(const int* __restrict__ src, const int* __restrict__ dst,
                         const int* __restrict__ ocounts, const int* __restrict__ blockSum,
                         int* __restrict__ ebuf, int E, int nbuck) {
    __shared__ int cur[1024];
    for (int j = threadIdx.x; j < nbuck; j += blockDim.x) {
        int idx = j * gridDim.x + blockIdx.x;
        cur[j] = ocounts[idx] + blockSum[idx >> 8];
    }
    __syncthreads();
    int per = (E + gridDim.x - 1) / gridDim.x;
    int i0 = blockIdx.x * per, i1 = min(E, i0 + per);
    for (int i = i0 + threadIdx.x; i < i1; i += blockDim.x) {
        int d = dst[i];
        int b = d >> 7;
        int pos = atomicAdd(&cur[b], 1);
        ebuf[pos] = src[i] | ((d & 127) << 17);
    }
}

// Fused csr-build + layer-1 gather (xacc-linearized, 32B L2-resident rows,
// LDS-resident csr, degree-sorted node order) + epilogue + gmax2 reduce.
// One 512-thread block per 128-node bucket; phase 2 uses 4 lanes per node
// (lane = head), depth-2 pipeline. Nodes are processed in degree-sorted
// order so each wave's 16 nodes have similar degree (minimal divergence).
__global__ void __launch_bounds__(512, 2)
fusedG1(const int* __restrict__ ebuf, const int* __restrict__ ocounts,
        const int* __restrict__ blockSum, const unsigned* __restrict__ gmax1,
        const unsigned* __restrict__ xa32, const float* __restrict__ adst1,
        const float* __restrict__ eloop1,
        const float* __restrict__ W1, const float* __restrict__ b1,
        const float* __restrict__ W2,
        const float* __restrict__ a_src2, const float* __restrict__ a_dst2,
        int* __restrict__ rowstart, int* __restrict__ deg, int* __restrict__ csr,
        uint4* __restrict__ h2p16,
        float* __restrict__ adst2, float* __restrict__ eloop2,
        unsigned* __restrict__ gmax2, int N, int E, int G, int nbuck) {
    int b = blockIdx.x;
    int idxb = b * G;
    int beg = ocounts[idxb] + blockSum[idxb >> 8];
    int end = E;
    if (b + 1 < nbuck) {
        int idx2 = (b + 1) * G;
        end = ocounts[idx2] + blockSum[idx2 >> 8];
    }
    int base = b << 7;
    int tid = threadIdx.x;

    __shared__ int cnt[128], sc[128], rloc[128], lloc[128], lcur[128];
    __shared__ int sidx[128];
    __shared__ int lcsr[LCAP];
    __shared__ float W1s[448], W2s[384], b1s[64];
    __shared__ unsigned bmax2s;

    if (tid == 0) bmax2s = 0u;
    if (tid < 128) cnt[tid] = 0;
    for (int j = tid; j < 448; j += 512) W1s[j] = W1[j];
    for (int j = tid; j < 384; j += 512) W2s[j] = W2[j];
    if (tid < 64) b1s[tid] = b1[tid];
    __syncthreads();
    for (int i = beg + tid; i < end; i += 512)
        atomicAdd(&cnt[ebuf[i] >> 17], 1);
    __syncthreads();
    if (tid < 128) sc[tid] = cnt[tid];
    __syncthreads();
    for (int off = 1; off < 128; off <<= 1) {
        int t = (tid < 128) ? sc[tid] : 0;
        int add = (tid >= off && tid < 128) ? sc[tid - off] : 0;
        __syncthreads();
        if (tid < 128) sc[tid] = t + add;
        __syncthreads();
    }
    if (tid < 128) {
        int ex = sc[tid] - cnt[tid];         // bucket-local exclusive scan
        lloc[tid] = ex;
        rloc[tid] = beg + ex;
        lcur[tid] = 0;
        sidx[tid] = tid;
        int node = base + tid;
        if (node < N) { rowstart[node] = beg + ex; deg[node] = cnt[tid]; }
    }
    __syncthreads();
    for (int i = beg + tid; i < end; i += 512) {
        int e = ebuf[i];
        int j = e >> 17;
        int s = e & 0x1FFFF;
        int pos = atomicAdd(&lcur[j], 1);
        int li = lloc[j] + pos;
        if (li < LCAP) lcsr[li] = s;         // LDS copy for phase 2
        csr[rloc[j] + pos] = s;              // global copy for gatherL2
    }

    // ---- Bitonic sort of node ids by degree (ascending): waves get
    //      similar-degree nodes -> minimal loop divergence in phase 2 ----
    for (int k = 2; k <= 128; k <<= 1) {
        for (int j = k >> 1; j > 0; j >>= 1) {
            __syncthreads();
            if (tid < 128) {
                int ixj = tid ^ j;
                if (ixj > tid) {
                    int a = sidx[tid], c = sidx[ixj];
                    bool asc = ((tid & k) == 0);
                    if ((cnt[a] > cnt[c]) == asc) {
                        sidx[tid] = c;
                        sidx[ixj] = a;
                    }
                }
            }
        }
    }
    __syncthreads();

    // ---- Phase 2: xacc gather, 4 lanes per node (lane = head), depth-2 ----
    int g = tid >> 2, h = tid & 3;
    int nl = sidx[g];
    int node = base + nl;
    if (node < N) {
        int rs = lloc[nl], grs = rloc[nl], dg = cnt[nl];
        float adh = adst1[node * 4 + h];
        float m = lrelu(decf(gmax1[h]) + adh);
        float z0 = __expf(eloop1[node * 4 + h] - m);
        float den = z0;

        const uint4* xav = (const uint4*)xa32;   // row = 2 uint4 (32B)
        uint4 S0 = xav[(size_t)node * 2];
        float2 s01 = __half22float2(*(const __half2*)&S0.x);
        float2 s23 = __half22float2(*(const __half2*)&S0.y);
        float2 s45 = __half22float2(*(const __half2*)&S0.z);
        float2 s6_ = __half22float2(*(const __half2*)&S0.w);
        float xc0 = z0 * s01.x, xc1 = z0 * s01.y, xc2 = z0 * s23.x, xc3 = z0 * s23.y;
        float xc4 = z0 * s45.x, xc5 = z0 * s45.y, xc6 = z0 * s6_.x;

        if (dg > 0) {
            int iB = (dg > 1) ? 1 : 0;
            int sA = (rs < LCAP) ? lcsr[rs] : csr[grs];
            int liB = rs + iB;
            int sB = (liB < LCAP) ? lcsr[liB] : csr[grs + iB];
            uint4 A0 = xav[(size_t)sA * 2], A1 = xav[(size_t)sA * 2 + 1];
            uint4 B0 = xav[(size_t)sB * 2], B1 = xav[(size_t)sB * 2 + 1];
            for (int k = 0; k < dg; ++k) {
                int k2 = (k + 2 < dg) ? k + 2 : dg - 1;
                int liC = rs + k2;
                int sC = (liC < LCAP) ? lcsr[liC] : csr[grs + k2];
                uint4 C0 = xav[(size_t)sC * 2], C1 = xav[(size_t)sC * 2 + 1];
                float av = __uint_as_float(h == 0 ? A1.x : h == 1 ? A1.y
                                         : h == 2 ? A1.z : A1.w);
                float z = __expf(lrelu(av + adh) - m);
                den += z;
                float2 p01 = __half22float2(*(const __half2*)&A0.x);
                float2 p23 = __half22float2(*(const __half2*)&A0.y);
                float2 p45 = __half22float2(*(const __half2*)&A0.z);
                float2 p6_ = __half22float2(*(const __half2*)&A0.w);
                xc0 = fmaf(z, p01.x, xc0); xc1 = fmaf(z, p01.y, xc1);
                xc2 = fmaf(z, p23.x, xc2); xc3 = fmaf(z, p23.y, xc3);
                xc4 = fmaf(z, p45.x, xc4); xc5 = fmaf(z, p45.y, xc5);
                xc6 = fmaf(z, p6_.x, xc6);
                A0 = B0; A1 = B1;
                B0 = C0; B1 = C1;
            }
        }

        // ---- Epilogue: v = (xacc/den)@W1 + b1, ELU, @W2, layer-2 logits ----
        float inv = 1.f / den;
        float xv0 = xc0 * inv, xv1 = xc1 * inv, xv2 = xc2 * inv, xv3 = xc3 * inv;
        float xv4 = xc4 * inv, xv5 = xc5 * inv, xv6 = xc6 * inv;
        float hh[6] = {0.f, 0.f, 0.f, 0.f, 0.f, 0.f};
        #pragma unroll
        for (int c = 0; c < 16; ++c) {
            int ch = h * 16 + c;
            const float* Wc = &W1s[ch];
            float v = xv0 * Wc[0] + xv1 * Wc[64] + xv2 * Wc[128] + xv3 * Wc[192]
                    + xv4 * Wc[256] + xv5 * Wc[320] + xv6 * Wc[384] + b1s[ch];
            v = v > 0.f ? v : __expf(v) - 1.f;   // ELU
            const float* W2c = &W2s[ch * 6];
            #pragma unroll
            for (int c2 = 0; c2 < 6; ++c2) hh[c2] = fmaf(v, W2c[c2], hh[c2]);
        }
        #pragma unroll
        for (int c2 = 0; c2 < 6; ++c2) {
            hh[c2] += __shfl_xor(hh[c2], 1);
            hh[c2] += __shfl_xor(hh[c2], 2);
        }
        float as = 0.f, ad = 0.f;
        #pragma unroll
        for (int c2 = 0; c2 < 6; ++c2) {
            as += hh[c2] * a_src2[c2];
            ad += hh[c2] * a_dst2[c2];
        }
        if (h == 0) {
            __half2 q0 = __floats2half2_rn(hh[0], hh[1]);
            __half2 q1 = __floats2half2_rn(hh[2], hh[3]);
            __half2 q2 = __floats2half2_rn(hh[4], hh[5]);
            __half2 q3 = __floats2half2_rn(as, 0.f);
            uint4 r;
            r.x = *(unsigned*)&q0; r.y = *(unsigned*)&q1;
            r.z = *(unsigned*)&q2; r.w = *(unsigned*)&q3;
            h2p16[node] = r;
            adst2[node] = ad;
            eloop2[node] = lrelu(as + ad);
            atomicMax(&bmax2s, encf(as));
        }
    }
    __syncthreads();
    if (tid == 0) atomicMax(gmax2, bmax2s);
}

// Layer-2 gather + log_softmax. 8 lanes per node (8 nodes/wave, 32/block):
// each lane walks ~deg/8 strided edges (independent chains -> real MLP),
// 3-level shfl reduction, one 16B request per edge.
__global__ void gatherL2(const int* __restrict__ csr, const int* __restrict__ rowstart,
                         const int* __restrict__ deg, const unsigned* __restrict__ gmax2,
                         const uint4* __restrict__ h2p16, const float* __restrict__ adst2,
                         const float* __restrict__ eloop2,
                         const float* __restrict__ b2, float* __restrict__ out, int N) {
    int node = blockIdx.x * 32 + (threadIdx.x >> 3);
    if (node >= N) return;
    int lane = threadIdx.x & 7;
    int rs = rowstart[node], dg = deg[node];

    float adn = adst2[node];
    float m = lrelu(decf(*gmax2) + adn);

    float den = 0.f;
    float a0 = 0.f, a1 = 0.f, a2 = 0.f, a3 = 0.f, a4 = 0.f, a5 = 0.f;
    if (lane == 0) {
        float z0 = __expf(eloop2[node] - m);
        den = z0;
        uint4 r = h2p16[node];
        float2 p01 = __half22float2(*(const __half2*)&r.x);
        float2 p23 = __half22float2(*(const __half2*)&r.y);
        float2 p45 = __half22float2(*(const __half2*)&r.z);
        a0 = z0 * p01.x; a1 = z0 * p01.y; a2 = z0 * p23.x;
        a3 = z0 * p23.y; a4 = z0 * p45.x; a5 = z0 * p45.y;
    }
    for (int k = lane; k < dg; k += 8) {
        int s = csr[rs + k];
        uint4 r = h2p16[s];
        float2 p01 = __half22float2(*(const __half2*)&r.x);
        float2 p23 = __half22float2(*(const __half2*)&r.y);
        float2 p45 = __half22float2(*(const __half2*)&r.z);
        float2 p6_ = __half22float2(*(const __half2*)&r.w);
        float z = __expf(lrelu(p6_.x + adn) - m);   // p6_.x = asrc2[s]
        den += z;
        a0 = fmaf(z, p01.x, a0); a1 = fmaf(z, p01.y, a1); a2 = fmaf(z, p23.x, a2);
        a3 = fmaf(z, p23.y, a3); a4 = fmaf(z, p45.x, a4); a5 = fmaf(z, p45.y, a5);
    }
    #pragma unroll
    for (int mm = 4; mm >= 1; mm >>= 1) {
        den += __shfl_xor(den, mm);
        a0 += __shfl_xor(a0, mm); a1 += __shfl_xor(a1, mm); a2 += __shfl_xor(a2, mm);
        a3 += __shfl_xor(a3, mm); a4 += __shfl_xor(a4, mm); a5 += __shfl_xor(a5, mm);
    }
    if (lane == 0) {
        float inv = 1.f / den;
        float v[6] = { a0 * inv + b2[0], a1 * inv + b2[1], a2 * inv + b2[2],
                       a3 * inv + b2[3], a4 * inv + b2[4], a5 * inv + b2[5] };
        float mxv = -1e30f;
        #pragma unroll
        for (int cc = 0; cc < 6; cc++) mxv = fmaxf(mxv, v[cc]);
        float ssum = 0.f;
        #pragma unroll
        for (int cc = 0; cc < 6; cc++) ssum += __expf(v[cc] - mxv);
        float lse = mxv + logf(ssum);
        #pragma unroll
        for (int cc = 0; cc < 6; cc++) out[node * 6 + cc] = v[cc] - lse;
    }
}

extern "C" void kernel_launch(void* const* d_in, const int* in_sizes, int n_in,
                              void* d_out, int out_size, void* d_ws, size_t ws_size,
                              hipStream_t stream) {
    const float* x      = (const float*)d_in[0];
    const int*   ei     = (const int*)d_in[1];
    const float* W1     = (const float*)d_in[2];
    const float* a_src1 = (const float*)d_in[3];
    const float* a_dst1 = (const float*)d_in[4];
    const float* b1     = (const float*)d_in[5];
    const float* W2     = (const float*)d_in[6];
    const float* a_src2 = (const float*)d_in[7];
    const float* a_dst2 = (const float*)d_in[8];
    const float* b2     = (const float*)d_in[9];
    float* out = (float*)d_out;

    const int N = in_sizes[0] / 7;
    const int E = in_sizes[1] / 2;
    const int* src = ei;
    const int* dst = ei + E;
    const int nbuck = (N + 127) >> 7;       // 128-node buckets
    const int G = 256;                      // sort blocks
    const int M = nbuck * G;                // counts entries (<= 262144)

    // Workspace layout
    float* w = (float*)d_ws;
    unsigned* xa32 = (unsigned*)w;  w += (size_t)N * 8;  // 32B packed rows
    uint4* h2p16 = (uint4*)w;       w += (size_t)N * 4;  // 16B packed L2 rows
    float* adst1  = w;  w += (size_t)N * 4;
    float* eloop1 = w;  w += (size_t)N * 4;
    float* adst2  = w;  w += (size_t)N;
    float* eloop2 = w;  w += (size_t)N;
    int* ip = (int*)w;
    int* ebuf     = ip; ip += E;
    int* deg      = ip; ip += N;
    int* rowstart = ip; ip += N;
    int* blockSum = ip; ip += 1024;
    int* csr      = ip; ip += E;
    int* counts   = ip; ip += M;
    int* ocounts  = ip; ip += M;
    unsigned* gmax1 = (unsigned*)ip; ip += 4;
    unsigned* gmax2 = (unsigned*)ip; ip += 4;

    int nbM = (M + 255) / 256;

    // zero gmax1[4] + gmax2 (encoded bottom = 0u)
    hipMemsetAsync(gmax1, 0, 8 * sizeof(unsigned), stream);
    // merged phaseA + dst histogram + gmax1 reduce (grid must equal G)
    phaseAH<<<dim3(G), 512, 0, stream>>>(x, W1, a_src1, a_dst1, dst,
                                         xa32, adst1, eloop1,
                                         counts, gmax1, N, E, nbuck);
    scan1<<<dim3(nbM), 256, 0, stream>>>(counts, ocounts, blockSum, M);
    scan2<<<1, 1024, 0, stream>>>(blockSum, nbM);
    scatterS<<<dim3(G), 512, 0, stream>>>(src, dst, ocounts, blockSum, ebuf, E, nbuck);
    // fused csr-build + xacc-linearized layer-1 gather + gmax2 reduce
    fusedG1<<<dim3(nbuck), 512, 0, stream>>>(ebuf, ocounts, blockSum, gmax1,
                                             xa32, adst1, eloop1,
                                             W1, b1, W2, a_src2, a_dst2,
                                             rowstart, deg, csr,
                                             h2p16, adst2, eloop2,
                                             gmax2, N, E, G, nbuck);
    gatherL2<<<dim3((N + 31) / 32), 256, 0, stream>>>(csr, rowstart, deg, gmax2,
                                                      h2p16, adst2, eloop2, b2, out, N);
}

// Round 25
// 168.933 us; speedup vs baseline: 1.0344x; 1.0344x over previous
//
#include <hip/hip_runtime.h>
#include <hip/hip_fp16.h>
#include <math.h>

#define NEG_SLOPE 0.2f
#define LCAP 8192   // LDS csr capacity per bucket (avg 4096)

__device__ __forceinline__ float lrelu(float x) { return x > 0.f ? x : NEG_SLOPE * x; }

// Order-preserving float<->uint encoding so unsigned atomicMax == float max.
__device__ __forceinline__ unsigned encf(float f) {
    unsigned u = __float_as_uint(f);
    return (u & 0x80000000u) ? ~u : (u | 0x80000000u);
}
__device__ __forceinline__ float decf(unsigned u) {
    return __uint_as_float((u & 0x80000000u) ? (u ^ 0x80000000u) : ~u);
}

// Phase A + dst-histogram + gmax1 block-reduction (merged).
// Grid MUST be G=256 blocks x 512 threads: counts[j*G + blockIdx] layout is
// shared with scatterS. gmax1 must be zeroed (memset) before this kernel.
// Packs the per-node 32B gather row: xa32[8 words] =
//   {x[0..6] fp16 + pad (4 words), asrc1[0..3] f32 (4 words)}.
__global__ void __launch_bounds__(512)
phaseAH(const float* __restrict__ x, const float* __restrict__ W1,
        const float* __restrict__ a_src, const float* __restrict__ a_dst,
        const int* __restrict__ dst,
        unsigned* __restrict__ xa32, float* __restrict__ adst1,
        float* __restrict__ eloop1,
        int* __restrict__ counts, unsigned* __restrict__ gmax1,
        int N, int E, int nbuck) {
    __shared__ int hist[1024];
    __shared__ unsigned bmax1[4];
    int tid = threadIdx.x;
    for (int j = tid; j < nbuck; j += 512) hist[j] = 0;
    if (tid < 4) bmax1[tid] = 0u;
    __syncthreads();

    // histogram over this block's edge slice (bucket = dst >> 7)
    int per = (E + gridDim.x - 1) / gridDim.x;
    int i0 = blockIdx.x * per, i1 = min(E, i0 + per);
    for (int i = i0 + tid; i < i1; i += 512)
        atomicAdd(&hist[dst[i] >> 7], 1);

    // phaseA over this block's node slice (wave per node)
    int npb = (N + gridDim.x - 1) / gridDim.x;
    int n0 = blockIdx.x * npb, n1 = min(N, n0 + npb);
    int lane = tid & 63;
    int head = lane >> 4, c = lane & 15;
    for (int node = n0 + (tid >> 6); node < n1; node += 8) {
        float h = 0.f;
        #pragma unroll
        for (int k = 0; k < 7; k++) h += x[node * 7 + k] * W1[k * 64 + lane];

        float s = h * a_src[lane];
        float d = h * a_dst[lane];
        #pragma unroll
        for (int m = 8; m >= 1; m >>= 1) {
            s += __shfl_xor(s, m);
            d += __shfl_xor(d, m);
        }
        // pack x as fp16 pairs into words 0..3 of the row
        float xl = (lane < 7) ? x[node * 7 + lane] : 0.f;
        float xn = __shfl(xl, lane + 1);
        if (lane < 8 && !(lane & 1)) {
            __half2 hp = __floats2half2_rn(xl, xn);
            xa32[(size_t)node * 8 + (lane >> 1)] = *(unsigned*)&hp;
        }
        if (c == 0) {
            xa32[(size_t)node * 8 + 4 + head] = __float_as_uint(s);
            adst1[node * 4 + head] = d;
            eloop1[node * 4 + head] = lrelu(s + d);
            atomicMax(&bmax1[head], encf(s));   // LDS block-level max
        }
    }
    __syncthreads();
    for (int j = tid; j < nbuck; j += 512)
        counts[j * gridDim.x + blockIdx.x] = hist[j];
    if (tid < 4) atomicMax(&gmax1[tid], bmax1[tid]);
}

// Exclusive scan over counts (2 kernels; final add folded into consumers).
__global__ void scan1(const int* __restrict__ in, int* __restrict__ outv,
                      int* __restrict__ blockSum, int n) {
    __shared__ int sm[256];
    int tid = threadIdx.x;
    int i = blockIdx.x * 256 + tid;
    int v = (i < n) ? in[i] : 0;
    sm[tid] = v;
    __syncthreads();
    for (int off = 1; off < 256; off <<= 1) {
        int t = sm[tid];
        int add = (tid >= off) ? sm[tid - off] : 0;
        __syncthreads();
        sm[tid] = t + add;
        __syncthreads();
    }
    if (i < n) outv[i] = sm[tid] - v;     // block-local exclusive
    if (tid == 255) blockSum[blockIdx.x] = sm[255];
}

__global__ void scan2(int* __restrict__ blockSum, int nb) {
    __shared__ int sm[1024];
    int tid = threadIdx.x;
    int v = (tid < nb) ? blockSum[tid] : 0;
    sm[tid] = v;
    __syncthreads();
    for (int off = 1; off < 1024; off <<= 1) {
        int t = sm[tid];
        int add = (tid >= off) ? sm[tid - off] : 0;
        __syncthreads();
        sm[tid] = t + add;
        __syncthreads();
    }
    if (tid < nb) blockSum[tid] = sm[tid] - v;  // exclusive
}

// scatterS: LDS cursors seeded from (ocounts + blockSum); LDS atomics only.
// ebuf entry packed: src (17b) | local-node-id (7b) << 17.
__global__ void scatterS(const int* __restrict__ src, const int* __restrict__ dst,
                         const int* __restrict__ ocounts, const int* __restrict__ blockSum,
                         int* __restrict__ ebuf, int E, int nbuck) {
    __shared__ int cur[1024];
    for (int j = threadIdx.x; j < nbuck; j += blockDim.x) {
        int idx = j * gridDim.x + blockIdx.x;
        cur[j] = ocounts[idx] + blockSum[idx >> 8];
    }
    __syncthreads();
    int per = (E + gridDim.x - 1) / gridDim.x;
    int i0 = blockIdx.x * per, i1 = min(E, i0 + per);
    for (int i = i0 + threadIdx.x; i < i1; i += blockDim.x) {
        int d = dst[i];
        int b = d >> 7;
        int pos = atomicAdd(&cur[b], 1);
        ebuf[pos] = src[i] | ((d & 127) << 17);
    }
}

// Fused csr-build + layer-1 gather (xacc-linearized, 32B L2-resident rows,
// LDS-resident csr) + epilogue + gmax2 reduce. One 512-thread block per
// 128-node bucket; phase 2 uses 4 lanes per node (lane = head), depth-2
// pipeline. Epilogue packs the 16B fp16 layer-2 row h2p16[node] =
//   {h2[0..5], asrc2} as 7 halves + pad.
__global__ void __launch_bounds__(512, 2)
fusedG1(const int* __restrict__ ebuf, const int* __restrict__ ocounts,
        const int* __restrict__ blockSum, const unsigned* __restrict__ gmax1,
        const unsigned* __restrict__ xa32, const float* __restrict__ adst1,
        const float* __restrict__ eloop1,
        const float* __restrict__ W1, const float* __restrict__ b1,
        const float* __restrict__ W2,
        const float* __restrict__ a_src2, const float* __restrict__ a_dst2,
        int* __restrict__ rowstart, int* __restrict__ deg, int* __restrict__ csr,
        uint4* __restrict__ h2p16,
        float* __restrict__ adst2, float* __restrict__ eloop2,
        unsigned* __restrict__ gmax2, int N, int E, int G, int nbuck) {
    int b = blockIdx.x;
    int idxb = b * G;
    int beg = ocounts[idxb] + blockSum[idxb >> 8];
    int end = E;
    if (b + 1 < nbuck) {
        int idx2 = (b + 1) * G;
        end = ocounts[idx2] + blockSum[idx2 >> 8];
    }
    int base = b << 7;
    int tid = threadIdx.x;

    __shared__ int cnt[128], sc[128], rloc[128], lloc[128], lcur[128];
    __shared__ int lcsr[LCAP];
    __shared__ float W1s[448], W2s[384], b1s[64];
    __shared__ unsigned bmax2s;

    if (tid == 0) bmax2s = 0u;
    if (tid < 128) cnt[tid] = 0;
    for (int j = tid; j < 448; j += 512) W1s[j] = W1[j];
    for (int j = tid; j < 384; j += 512) W2s[j] = W2[j];
    if (tid < 64) b1s[tid] = b1[tid];
    __syncthreads();
    for (int i = beg + tid; i < end; i += 512)
        atomicAdd(&cnt[ebuf[i] >> 17], 1);
    __syncthreads();
    if (tid < 128) sc[tid] = cnt[tid];
    __syncthreads();
    for (int off = 1; off < 128; off <<= 1) {
        int t = (tid < 128) ? sc[tid] : 0;
        int add = (tid >= off && tid < 128) ? sc[tid - off] : 0;
        __syncthreads();
        if (tid < 128) sc[tid] = t + add;
        __syncthreads();
    }
    if (tid < 128) {
        int ex = sc[tid] - cnt[tid];         // bucket-local exclusive scan
        lloc[tid] = ex;
        rloc[tid] = beg + ex;
        lcur[tid] = 0;
        int node = base + tid;
        if (node < N) { rowstart[node] = beg + ex; deg[node] = cnt[tid]; }
    }
    __syncthreads();
    for (int i = beg + tid; i < end; i += 512) {
        int e = ebuf[i];
        int j = e >> 17;
        int s = e & 0x1FFFF;
        int pos = atomicAdd(&lcur[j], 1);
        int li = lloc[j] + pos;
        if (li < LCAP) lcsr[li] = s;         // LDS copy for phase 2
        csr[rloc[j] + pos] = s;              // global copy for gatherL2
    }
    __syncthreads();

    // ---- Phase 2: xacc gather, 4 lanes per node (lane = head), depth-2 ----
    int g = tid >> 2, h = tid & 3;
    int node = base + g;
    if (node < N) {
        int rs = lloc[g], grs = rloc[g], dg = cnt[g];
        float adh = adst1[node * 4 + h];
        float m = lrelu(decf(gmax1[h]) + adh);
        float z0 = __expf(eloop1[node * 4 + h] - m);
        float den = z0;

        const uint4* xav = (const uint4*)xa32;   // row = 2 uint4 (32B)
        uint4 S0 = xav[(size_t)node * 2];
        float2 s01 = __half22float2(*(const __half2*)&S0.x);
        float2 s23 = __half22float2(*(const __half2*)&S0.y);
        float2 s45 = __half22float2(*(const __half2*)&S0.z);
        float2 s6_ = __half22float2(*(const __half2*)&S0.w);
        float xc0 = z0 * s01.x, xc1 = z0 * s01.y, xc2 = z0 * s23.x, xc3 = z0 * s23.y;
        float xc4 = z0 * s45.x, xc5 = z0 * s45.y, xc6 = z0 * s6_.x;

        if (dg > 0) {
            int iB = (dg > 1) ? 1 : 0;
            int sA = (rs < LCAP) ? lcsr[rs] : csr[grs];
            int liB = rs + iB;
            int sB = (liB < LCAP) ? lcsr[liB] : csr[grs + iB];
            uint4 A0 = xav[(size_t)sA * 2], A1 = xav[(size_t)sA * 2 + 1];
            uint4 B0 = xav[(size_t)sB * 2], B1 = xav[(size_t)sB * 2 + 1];
            for (int k = 0; k < dg; ++k) {
                int k2 = (k + 2 < dg) ? k + 2 : dg - 1;
                int liC = rs + k2;
                int sC = (liC < LCAP) ? lcsr[liC] : csr[grs + k2];
                uint4 C0 = xav[(size_t)sC * 2], C1 = xav[(size_t)sC * 2 + 1];
                float av = __uint_as_float(h == 0 ? A1.x : h == 1 ? A1.y
                                         : h == 2 ? A1.z : A1.w);
                float z = __expf(lrelu(av + adh) - m);
                den += z;
                float2 p01 = __half22float2(*(const __half2*)&A0.x);
                float2 p23 = __half22float2(*(const __half2*)&A0.y);
                float2 p45 = __half22float2(*(const __half2*)&A0.z);
                float2 p6_ = __half22float2(*(const __half2*)&A0.w);
                xc0 = fmaf(z, p01.x, xc0); xc1 = fmaf(z, p01.y, xc1);
                xc2 = fmaf(z, p23.x, xc2); xc3 = fmaf(z, p23.y, xc3);
                xc4 = fmaf(z, p45.x, xc4); xc5 = fmaf(z, p45.y, xc5);
                xc6 = fmaf(z, p6_.x, xc6);
                A0 = B0; A1 = B1;
                B0 = C0; B1 = C1;
            }
        }

        // ---- Epilogue: v = (xacc/den)@W1 + b1, ELU, @W2, layer-2 logits ----
        float inv = 1.f / den;
        float xv0 = xc0 * inv, xv1 = xc1 * inv, xv2 = xc2 * inv, xv3 = xc3 * inv;
        float xv4 = xc4 * inv, xv5 = xc5 * inv, xv6 = xc6 * inv;
        float hh[6] = {0.f, 0.f, 0.f, 0.f, 0.f, 0.f};
        #pragma unroll
        for (int c = 0; c < 16; ++c) {
            int ch = h * 16 + c;
            const float* Wc = &W1s[ch];
            float v = xv0 * Wc[0] + xv1 * Wc[64] + xv2 * Wc[128] + xv3 * Wc[192]
                    + xv4 * Wc[256] + xv5 * Wc[320] + xv6 * Wc[384] + b1s[ch];
            v = v > 0.f ? v : __expf(v) - 1.f;   // ELU
            const float* W2c = &W2s[ch * 6];
            #pragma unroll
            for (int c2 = 0; c2 < 6; ++c2) hh[c2] = fmaf(v, W2c[c2], hh[c2]);
        }
        #pragma unroll
        for (int c2 = 0; c2 < 6; ++c2) {
            hh[c2] += __shfl_xor(hh[c2], 1);
            hh[c2] += __shfl_xor(hh[c2], 2);
        }
        float as = 0.f, ad = 0.f;
        #pragma unroll
        for (int c2 = 0; c2 < 6; ++c2) {
            as += hh[c2] * a_src2[c2];
            ad += hh[c2] * a_dst2[c2];
        }
        if (h == 0) {
            __half2 q0 = __floats2half2_rn(hh[0], hh[1]);
            __half2 q1 = __floats2half2_rn(hh[2], hh[3]);
            __half2 q2 = __floats2half2_rn(hh[4], hh[5]);
            __half2 q3 = __floats2half2_rn(as, 0.f);
            uint4 r;
            r.x = *(unsigned*)&q0; r.y = *(unsigned*)&q1;
            r.z = *(unsigned*)&q2; r.w = *(unsigned*)&q3;
            h2p16[node] = r;
            adst2[node] = ad;
            eloop2[node] = lrelu(as + ad);
            atomicMax(&bmax2s, encf(as));
        }
    }
    __syncthreads();
    if (tid == 0) atomicMax(gmax2, bmax2s);
}

// Layer-2 gather + log_softmax. 8 lanes per node (8 nodes/wave, 32/block):
// each lane walks ~deg/8 strided edges (independent chains -> real MLP),
// 3-level shfl reduction, one 16B request per edge.
__global__ void gatherL2(const int* __restrict__ csr, const int* __restrict__ rowstart,
                         const int* __restrict__ deg, const unsigned* __restrict__ gmax2,
                         const uint4* __restrict__ h2p16, const float* __restrict__ adst2,
                         const float* __restrict__ eloop2,
                         const float* __restrict__ b2, float* __restrict__ out, int N) {
    int node = blockIdx.x * 32 + (threadIdx.x >> 3);
    if (node >= N) return;
    int lane = threadIdx.x & 7;
    int rs = rowstart[node], dg = deg[node];

    float adn = adst2[node];
    float m = lrelu(decf(*gmax2) + adn);

    float den = 0.f;
    float a0 = 0.f, a1 = 0.f, a2 = 0.f, a3 = 0.f, a4 = 0.f, a5 = 0.f;
    if (lane == 0) {
        float z0 = __expf(eloop2[node] - m);
        den = z0;
        uint4 r = h2p16[node];
        float2 p01 = __half22float2(*(const __half2*)&r.x);
        float2 p23 = __half22float2(*(const __half2*)&r.y);
        float2 p45 = __half22float2(*(const __half2*)&r.z);
        a0 = z0 * p01.x; a1 = z0 * p01.y; a2 = z0 * p23.x;
        a3 = z0 * p23.y; a4 = z0 * p45.x; a5 = z0 * p45.y;
    }
    for (int k = lane; k < dg; k += 8) {
        int s = csr[rs + k];
        uint4 r = h2p16[s];
        float2 p01 = __half22float2(*(const __half2*)&r.x);
        float2 p23 = __half22float2(*(const __half2*)&r.y);
        float2 p45 = __half22float2(*(const __half2*)&r.z);
        float2 p6_ = __half22float2(*(const __half2*)&r.w);
        float z = __expf(lrelu(p6_.x + adn) - m);   // p6_.x = asrc2[s]
        den += z;
        a0 = fmaf(z, p01.x, a0); a1 = fmaf(z, p01.y, a1); a2 = fmaf(z, p23.x, a2);
        a3 = fmaf(z, p23.y, a3); a4 = fmaf(z, p45.x, a4); a5 = fmaf(z, p45.y, a5);
    }
    #pragma unroll
    for (int mm = 4; mm >= 1; mm >>= 1) {
        den += __shfl_xor(den, mm);
        a0 += __shfl_xor(a0, mm); a1 += __shfl_xor(a1, mm); a2 += __shfl_xor(a2, mm);
        a3 += __shfl_xor(a3, mm); a4 += __shfl_xor(a4, mm); a5 += __shfl_xor(a5, mm);
    }
    if (lane == 0) {
        float inv = 1.f / den;
        float v[6] = { a0 * inv + b2[0], a1 * inv + b2[1], a2 * inv + b2[2],
                       a3 * inv + b2[3], a4 * inv + b2[4], a5 * inv + b2[5] };
        float mxv = -1e30f;
        #pragma unroll
        for (int cc = 0; cc < 6; cc++) mxv = fmaxf(mxv, v[cc]);
        float ssum = 0.f;
        #pragma unroll
        for (int cc = 0; cc < 6; cc++) ssum += __expf(v[cc] - mxv);
        float lse = mxv + logf(ssum);
        #pragma unroll
        for (int cc = 0; cc < 6; cc++) out[node * 6 + cc] = v[cc] - lse;
    }
}

extern "C" void kernel_launch(void* const* d_in, const int* in_sizes, int n_in,
                              void* d_out, int out_size, void* d_ws, size_t ws_size,
                              hipStream_t stream) {
    const float* x      = (const float*)d_in[0];
    const int*   ei     = (const int*)d_in[1];
    const float* W1     = (const float*)d_in[2];
    const float* a_src1 = (const float*)d_in[3];
    const float* a_dst1 = (const float*)d_in[4];
    const float* b1     = (const float*)d_in[5];
    const float* W2     = (const float*)d_in[6];
    const float* a_src2 = (const float*)d_in[7];
    const float* a_dst2 = (const float*)d_in[8];
    const float* b2     = (const float*)d_in[9];
    float* out = (float*)d_out;

    const int N = in_sizes[0] / 7;
    const int E = in_sizes[1] / 2;
    const int* src = ei;
    const int* dst = ei + E;
    const int nbuck = (N + 127) >> 7;       // 128-node buckets
    const int G = 256;                      // sort blocks
    const int M = nbuck * G;                // counts entries (<= 262144)

    // Workspace layout
    float* w = (float*)d_ws;
    unsigned* xa32 = (unsigned*)w;  w += (size_t)N * 8;  // 32B packed rows
    uint4* h2p16 = (uint4*)w;       w += (size_t)N * 4;  // 16B packed L2 rows
    float* adst1  = w;  w += (size_t)N * 4;
    float* eloop1 = w;  w += (size_t)N * 4;
    float* adst2  = w;  w += (size_t)N;
    float* eloop2 = w;  w += (size_t)N;
    int* ip = (int*)w;
    int* ebuf     = ip; ip += E;
    int* deg      = ip; ip += N;
    int* rowstart = ip; ip += N;
    int* blockSum = ip; ip += 1024;
    int* csr      = ip; ip += E;
    int* counts   = ip; ip += M;
    int* ocounts  = ip; ip += M;
    unsigned* gmax1 = (unsigned*)ip; ip += 4;
    unsigned* gmax2 = (unsigned*)ip; ip += 4;

    int nbM = (M + 255) / 256;

    // zero gmax1[4] + gmax2 (encoded bottom = 0u)
    hipMemsetAsync(gmax1, 0, 8 * sizeof(unsigned), stream);
    // merged phaseA + dst histogram + gmax1 reduce (grid must equal G)
    phaseAH<<<dim3(G), 512, 0, stream>>>(x, W1, a_src1, a_dst1, dst,
                                         xa32, adst1, eloop1,
                                         counts, gmax1, N, E, nbuck);
    scan1<<<dim3(nbM), 256, 0, stream>>>(counts, ocounts, blockSum, M);
    scan2<<<1, 1024, 0, stream>>>(blockSum, nbM);
    scatterS<<<dim3(G), 512, 0, stream>>>(src, dst, ocounts, blockSum, ebuf, E, nbuck);
    // fused csr-build + xacc-linearized layer-1 gather + gmax2 reduce
    fusedG1<<<dim3(nbuck), 512, 0, stream>>>(ebuf, ocounts, blockSum, gmax1,
                                             xa32, adst1, eloop1,
                                             W1, b1, W2, a_src2, a_dst2,
                                             rowstart, deg, csr,
                                             h2p16, adst2, eloop2,
                                             gmax2, N, E, G, nbuck);
    gatherL2<<<dim3((N + 31) / 32), 256, 0, stream>>>(csr, rowstart, deg, gmax2,
                                                      h2p16, adst2, eloop2, b2, out, N);
}